// Round 3
// baseline (1255.098 us; speedup 1.0000x reference)
//
#include <hip/hip_runtime.h>
#include <hip/hip_fp16.h>

typedef _Float16 f16;
typedef _Float16 f16x4 __attribute__((ext_vector_type(4)));
typedef _Float16 f16x8 __attribute__((ext_vector_type(8)));
typedef float    f32x4 __attribute__((ext_vector_type(4)));

#define NEG_INF (-__builtin_inff())
#define AS1 __attribute__((address_space(1)))
#define AS3 __attribute__((address_space(3)))
#define GLOAD_LDS16(g, l) \
    __builtin_amdgcn_global_load_lds((AS1 const void*)(g), (AS3 void*)(l), 16, 0, 0)

// ---------------------------------------------------------------- converts
__global__ __launch_bounds__(256) void cvt_f32_f16(const float* __restrict__ in,
                                                   f16* __restrict__ out, int n4) {
    int i = blockIdx.x * 256 + threadIdx.x;
    if (i >= n4) return;
    float4 v = ((const float4*)in)[i];
    f16x4 h = {(f16)v.x, (f16)v.y, (f16)v.z, (f16)v.w};
    ((f16x4*)out)[i] = h;
}

// ---------------------------------------------------------------- GEMM C = A * Bt^T
// (unchanged from round 2: global_load_lds 16B staging, XOR source-permute swizzle)
template <typename CT>
__global__ __launch_bounds__(256) void gemm_bt(const f16* __restrict__ A,
                                               const f16* __restrict__ Bt,
                                               CT* __restrict__ C, int M, int N, int K) {
    __shared__ f16 As[128 * 32];
    __shared__ f16 Bs[128 * 32];
    const int tid  = threadIdx.x;
    const int wave = tid >> 6, lane = tid & 63;
    const int quad = lane >> 4, m16 = lane & 15;
    const int waveM = (wave >> 1) * 64, waveN = (wave & 1) * 64;
    const int bm = blockIdx.y * 128, bn = blockIdx.x * 128;

    f32x4 acc[4][4];
#pragma unroll
    for (int i = 0; i < 4; ++i)
#pragma unroll
        for (int j = 0; j < 4; ++j)
#pragma unroll
            for (int e = 0; e < 4; ++e) acc[i][j][e] = 0.f;

    const f16* gA[2]; const f16* gB[2]; f16* lA[2]; f16* lB[2];
#pragma unroll
    for (int it = 0; it < 2; ++it) {
        int slot = wave * 128 + it * 64 + lane;
        int row  = slot >> 2;
        int c    = (slot - (row >> 1)) & 3;          // inverse swizzle
        gA[it] = A  + (size_t)(bm + row) * K + c * 8;
        gB[it] = Bt + (size_t)(bn + row) * K + c * 8;
        lA[it] = As + (size_t)(wave * 128 + it * 64) * 8;
        lB[it] = Bs + (size_t)(wave * 128 + it * 64) * 8;
    }
    const f16* apf[4]; const f16* bpf[4];
#pragma unroll
    for (int t = 0; t < 4; ++t) {
        int rowA = waveM + t * 16 + m16;
        int rowB = waveN + t * 16 + m16;
        apf[t] = As + rowA * 32 + (((quad + (rowA >> 1)) & 3) * 8);
        bpf[t] = Bs + rowB * 32 + (((quad + (rowB >> 1)) & 3) * 8);
    }

    for (int k0 = 0; k0 < K; k0 += 32) {
        __syncthreads();
#pragma unroll
        for (int it = 0; it < 2; ++it) {
            GLOAD_LDS16(gA[it] + k0, lA[it]);
            GLOAD_LDS16(gB[it] + k0, lB[it]);
        }
        __syncthreads();
        f16x8 af[4], bf[4];
#pragma unroll
        for (int t = 0; t < 4; ++t) af[t] = *(const f16x8*)apf[t];
#pragma unroll
        for (int t = 0; t < 4; ++t) bf[t] = *(const f16x8*)bpf[t];
#pragma unroll
        for (int i = 0; i < 4; ++i)
#pragma unroll
            for (int j = 0; j < 4; ++j)
                acc[i][j] = __builtin_amdgcn_mfma_f32_16x16x32_f16(af[i], bf[j], acc[i][j], 0, 0, 0);
    }

#pragma unroll
    for (int i = 0; i < 4; ++i)
#pragma unroll
        for (int r = 0; r < 4; ++r) {
            int row = bm + waveM + i * 16 + quad * 4 + r;
#pragma unroll
            for (int j = 0; j < 4; ++j) {
                int col = bn + waveN + j * 16 + m16;
                C[(size_t)row * N + col] = (CT)acc[i][j][r];
            }
        }
}

// ---------------------------------------------------------------- RoPE (q,k only)
// Paged cache scatter+gather through an injective block_table is the identity on
// (b,s) -> we skip the cache entirely. qkv row: q 0:4096 | k 4096:5120 | v 5120:6144.
// qh: [B,NH,S,HD]; kk: [B,NKV,S,HD].
__global__ __launch_bounds__(256) void rope_qk(const f16* __restrict__ qkv,
                                               const float* __restrict__ freqs,
                                               f16* __restrict__ qh,
                                               f16* __restrict__ kk) {
    int idx  = blockIdx.x * 256 + threadIdx.x;     // B*S*40heads*64pairs
    int row  = idx / 2560;
    int p    = idx - row * 2560;
    int b    = row >> 11, s = row & 2047;
    int head = p >> 6, i = p & 63;
    const f16* src = qkv + (size_t)row * 6144 + head * 128 + 2 * i;
    float v0 = (float)src[0], v1 = (float)src[1];
    float c  = freqs[s * 128 + 2 * i];
    float sn = freqs[s * 128 + 2 * i + 1];
    float r0 = v0 * c - v1 * sn;
    float r1 = v1 * c + v0 * sn;
    f16* dst = (head < 32)
        ? qh + (((size_t)(b * 32 + head)) * 2048 + s) * 128 + 2 * i
        : kk + (((size_t)(b * 8 + head - 32)) * 2048 + s) * 128 + 2 * i;
    dst[0] = (f16)r0; dst[1] = (f16)r1;
}

// ---------------------------------------------------------------- V transpose (LDS-tiled)
// vvt[b][kvh][d][s] <- qkv[(b*S+s)*6144 + 5120 + kvh*128 + d]; both sides coalesced.
__global__ __launch_bounds__(256) void transpose_v(const f16* __restrict__ qkv,
                                                   f16* __restrict__ vvt) {
    __shared__ f16 T[64][72];
    const int st = blockIdx.x, dt = blockIdx.y;
    const int b = blockIdx.z >> 3, kvh = blockIdx.z & 7;
    const int tid = threadIdx.x;
    const int sr = tid >> 3, c8 = (tid & 7) * 8;
#pragma unroll
    for (int rep = 0; rep < 2; ++rep) {
        int sl = rep * 32 + sr;
        *(f16x8*)&T[sl][c8] =
            *(const f16x8*)(qkv + (size_t)(b * 2048 + st * 64 + sl) * 6144
                            + 5120 + kvh * 128 + dt * 64 + c8);
    }
    __syncthreads();
#pragma unroll
    for (int rep = 0; rep < 2; ++rep) {
        int dl = rep * 32 + sr;
        f16x8 v;
#pragma unroll
        for (int j = 0; j < 8; ++j) v[j] = T[c8 + j][dl];
        *(f16x8*)(vvt + (((size_t)(b * 8 + kvh)) * 128 + dt * 64 + dl) * 2048
                  + st * 64 + c8) = v;
    }
}

// ---------------------------------------------------------------- flash attention v3
// grid (qt32=64 reversed, kvh=8, b=2), block 256 = 4 waves = the 4 GQA heads of this
// kvh group. All waves share the staged K/V tile (4x staging amortization). Each wave
// owns 32 q-rows (2 m-tiles) of its head -> every kf/vf b128 read feeds 2 MFMAs.
// P both-m-halves round-trip a wave-private 16-row LDS buffer sequentially (in-wave
// lgkm ordering); pf[2][2] held in regs so vf reads are shared across m. 2 barriers/tile.
__global__ __launch_bounds__(256, 3) void attn_fused(const f16* __restrict__ qh,
                                                     const f16* __restrict__ kk,
                                                     const f16* __restrict__ vvt,
                                                     const int* __restrict__ seqlens,
                                                     f16* __restrict__ out) {
    __shared__ f16 Ks[64 * 136];     // [key][d] stride 136 (2-way free)
    __shared__ f16 Vs[128][72];      // [d][key] stride 72 (2-way free)
    __shared__ f16 Ps[4 * 16 * 72];  // per-wave 16-row P transpose buffer
    const int qt = 63 - blockIdx.x;  // heavy-first
    const int kvh = blockIdx.y, b = blockIdx.z;
    const int tid = threadIdx.x, wave = tid >> 6, lane = tid & 63;
    const int quad = lane >> 4, m16 = lane & 15;
    const int h = kvh * 4 + wave;
    const int qbase = qt * 32;
    f16* Pw = Ps + wave * 16 * 72;

    // Q fragments for both m-tiles, resident all kernel
    f16x8 qf[2][4];
#pragma unroll
    for (int m = 0; m < 2; ++m) {
        const f16* qptr = qh + (((size_t)(b * 32 + h)) * 2048 + qbase + m * 16 + m16) * 128;
#pragma unroll
        for (int c = 0; c < 4; ++c) qf[m][c] = *(const f16x8*)(qptr + c * 32 + quad * 8);
    }

    float m_i[2][4], l_i[2][4];
    f32x4 oacc[2][8];
#pragma unroll
    for (int m = 0; m < 2; ++m) {
#pragma unroll
        for (int r = 0; r < 4; ++r) { m_i[m][r] = NEG_INF; l_i[m][r] = 0.f; }
#pragma unroll
        for (int dt = 0; dt < 8; ++dt)
#pragma unroll
            for (int e = 0; e < 4; ++e) oacc[m][dt][e] = 0.f;
    }

    const int seqlen = seqlens[b];
    int kmax = qbase + 32; if (seqlen < kmax) kmax = seqlen;
    const f16* kbp = kk  + ((size_t)(b * 8 + kvh) * 2048) * 128;
    const f16* vbp = vvt + ((size_t)(b * 8 + kvh) * 128) * 2048;

    for (int kt = 0; kt < kmax; kt += 64) {
        __syncthreads();   // prior iteration's Ks/Vs reads complete
#pragma unroll
        for (int it = 0; it < 4; ++it) {           // K tile: 64 keys x 128 d
            int g = it * 256 + tid;
            int r_ = g >> 4, c8 = (g & 15) * 8;
            *(f16x8*)&Ks[r_ * 136 + c8] = *(const f16x8*)(kbp + (size_t)(kt + r_) * 128 + c8);
        }
#pragma unroll
        for (int it = 0; it < 4; ++it) {           // V^T tile: 128 d x 64 keys
            int g = it * 256 + tid;
            int r_ = g >> 3, c8 = (g & 7) * 8;
            *(f16x8*)&Vs[r_][c8] = *(const f16x8*)(vbp + (size_t)r_ * 2048 + kt + c8);
        }
        __syncthreads();

        // S = Q K^T for both m-tiles; kf shared across m
        f32x4 sc[2][4];
#pragma unroll
        for (int m = 0; m < 2; ++m)
#pragma unroll
            for (int nt = 0; nt < 4; ++nt)
#pragma unroll
                for (int e = 0; e < 4; ++e) sc[m][nt][e] = 0.f;
#pragma unroll
        for (int nt = 0; nt < 4; ++nt)
#pragma unroll
            for (int c = 0; c < 4; ++c) {
                f16x8 kf = *(const f16x8*)&Ks[(nt * 16 + m16) * 136 + c * 32 + quad * 8];
#pragma unroll
                for (int m = 0; m < 2; ++m)
                    sc[m][nt] = __builtin_amdgcn_mfma_f32_16x16x32_f16(qf[m][c], kf, sc[m][nt], 0, 0, 0);
            }

        // online softmax per m-tile (rows = quad*4+r over 16-lane key groups)
#pragma unroll
        for (int m = 0; m < 2; ++m) {
            float mt[4] = {NEG_INF, NEG_INF, NEG_INF, NEG_INF};
#pragma unroll
            for (int nt = 0; nt < 4; ++nt) {
                int kpos = kt + nt * 16 + m16;
#pragma unroll
                for (int r = 0; r < 4; ++r) {
                    int qpos = qbase + m * 16 + quad * 4 + r;
                    float sx = sc[m][nt][r] * 0.08838834764831845f;
                    sx = (kpos <= qpos && kpos < seqlen) ? sx : NEG_INF;
                    sc[m][nt][r] = sx;
                    mt[r] = fmaxf(mt[r], sx);
                }
            }
#pragma unroll
            for (int off = 1; off < 16; off <<= 1)
#pragma unroll
                for (int r = 0; r < 4; ++r)
                    mt[r] = fmaxf(mt[r], __shfl_xor(mt[r], off, 64));
            float alpha[4], mm[4];
#pragma unroll
            for (int r = 0; r < 4; ++r) {
                float mo = m_i[m][r];
                float mn = fmaxf(mo, mt[r]);
                float mmr = fmaxf(mn, -1e30f);
                alpha[r] = __expf(mo - mmr);
                m_i[m][r] = mn;
                mm[r] = mmr;
            }
            float rs[4] = {0.f, 0.f, 0.f, 0.f};
#pragma unroll
            for (int nt = 0; nt < 4; ++nt)
#pragma unroll
                for (int r = 0; r < 4; ++r) {
                    float pv = __expf(sc[m][nt][r] - mm[r]);
                    sc[m][nt][r] = pv;
                    rs[r] += pv;
                }
#pragma unroll
            for (int off = 1; off < 16; off <<= 1)
#pragma unroll
                for (int r = 0; r < 4; ++r) rs[r] += __shfl_xor(rs[r], off, 64);
#pragma unroll
            for (int r = 0; r < 4; ++r) l_i[m][r] = l_i[m][r] * alpha[r] + rs[r];
#pragma unroll
            for (int dt = 0; dt < 8; ++dt)
#pragma unroll
                for (int r = 0; r < 4; ++r) oacc[m][dt][r] *= alpha[r];
        }

        // P (C-layout regs) -> wave-private LDS -> A-layout pf regs, both m sequentially
        f16x8 pf[2][2];
#pragma unroll
        for (int m = 0; m < 2; ++m) {
#pragma unroll
            for (int nt = 0; nt < 4; ++nt)
#pragma unroll
                for (int r = 0; r < 4; ++r)
                    Pw[(quad * 4 + r) * 72 + nt * 16 + m16] = (f16)sc[m][nt][r];
#pragma unroll
            for (int kc = 0; kc < 2; ++kc)
                pf[m][kc] = *(const f16x8*)&Pw[m16 * 72 + kc * 32 + quad * 8];
        }

        // O += P V, vf shared across m
#pragma unroll
        for (int dt = 0; dt < 8; ++dt)
#pragma unroll
            for (int kc = 0; kc < 2; ++kc) {
                f16x8 vf = *(const f16x8*)&Vs[dt * 16 + m16][kc * 32 + quad * 8];
#pragma unroll
                for (int m = 0; m < 2; ++m)
                    oacc[m][dt] = __builtin_amdgcn_mfma_f32_16x16x32_f16(pf[m][kc], vf, oacc[m][dt], 0, 0, 0);
            }
    }

    // normalize + write [B,S,NH*HD]
#pragma unroll
    for (int m = 0; m < 2; ++m)
#pragma unroll
        for (int r = 0; r < 4; ++r) {
            int qpos = qbase + m * 16 + quad * 4 + r;
            float inv = 1.0f / l_i[m][r];
            f16* op = out + ((size_t)b * 2048 + qpos) * 4096 + h * 128;
#pragma unroll
            for (int dt = 0; dt < 8; ++dt)
                op[dt * 16 + m16] = (f16)(oacc[m][dt][r] * inv);
        }
}

// ---------------------------------------------------------------- launch
extern "C" void kernel_launch(void* const* d_in, const int* in_sizes, int n_in,
                              void* d_out, int out_size, void* d_ws, size_t ws_size,
                              hipStream_t stream) {
    const float* x     = (const float*)d_in[0];   // [2,2048,4096]
    const float* wqkv  = (const float*)d_in[1];   // [6144,4096]
    const float* wo    = (const float*)d_in[2];   // [4096,4096]
    const float* freqs = (const float*)d_in[3];   // [2048,1,64,2]
    const int*   seql  = (const int*)d_in[7];     // [2]
    float* out = (float*)d_out;

    char* ws = (char*)d_ws;
    size_t o = 0;
    f16* xh    = (f16*)(ws + o); o += (size_t)4096 * 4096 * 2;   // reused as attn_h
    f16* wqkvh = (f16*)(ws + o); o += (size_t)6144 * 4096 * 2;
    f16* woh   = (f16*)(ws + o); o += (size_t)4096 * 4096 * 2;
    f16* qkvh  = (f16*)(ws + o); o += (size_t)4096 * 6144 * 2;
    f16* qhp   = (f16*)(ws + o); o += (size_t)4096 * 4096 * 2;
    f16* kkp   = (f16*)(ws + o); o += (size_t)4096 * 8 * 128 * 2;
    f16* vvt   = (f16*)(ws + o); o += (size_t)4096 * 8 * 128 * 2;
    f16* attnh = xh;  // xh dead after GEMM1

    cvt_f32_f16<<<16384, 256, 0, stream>>>(x, xh, 4194304);
    cvt_f32_f16<<<24576, 256, 0, stream>>>(wqkv, wqkvh, 6291456);
    cvt_f32_f16<<<16384, 256, 0, stream>>>(wo, woh, 4194304);

    gemm_bt<f16><<<dim3(48, 32), 256, 0, stream>>>(xh, wqkvh, qkvh, 4096, 6144, 4096);

    rope_qk<<<40960, 256, 0, stream>>>(qkvh, freqs, qhp, kkp);
    transpose_v<<<dim3(32, 2, 16), 256, 0, stream>>>(qkvh, vvt);

    attn_fused<<<dim3(64, 8, 2), 256, 0, stream>>>(qhp, kkp, vvt, seql, attnh);

    gemm_bt<float><<<dim3(32, 32), 256, 0, stream>>>(attnh, woh, out, 4096, 4096, 4096);
}

// Round 4
// 958.260 us; speedup vs baseline: 1.3098x; 1.3098x over previous
//
#include <hip/hip_runtime.h>
#include <hip/hip_fp16.h>

typedef _Float16 f16;
typedef _Float16 f16x4 __attribute__((ext_vector_type(4)));
typedef _Float16 f16x8 __attribute__((ext_vector_type(8)));
typedef float    f32x4 __attribute__((ext_vector_type(4)));

#define NEG_INF (-__builtin_inff())
#define AS1 __attribute__((address_space(1)))
#define AS3 __attribute__((address_space(3)))
#define GLOAD_LDS16(g, l) \
    __builtin_amdgcn_global_load_lds((AS1 const void*)(g), (AS3 void*)(l), 16, 0, 0)

// ---------------------------------------------------------------- converts
__global__ __launch_bounds__(256) void cvt_f32_f16(const float* __restrict__ in,
                                                   f16* __restrict__ out, int n4) {
    int i = blockIdx.x * 256 + threadIdx.x;
    if (i >= n4) return;
    float4 v = ((const float4*)in)[i];
    f16x4 h = {(f16)v.x, (f16)v.y, (f16)v.z, (f16)v.w};
    ((f16x4*)out)[i] = h;
}

// ---------------------------------------------------------------- GEMM C = A * Bt^T
// (unchanged: global_load_lds 16B staging, XOR source-permute swizzle)
template <typename CT>
__global__ __launch_bounds__(256) void gemm_bt(const f16* __restrict__ A,
                                               const f16* __restrict__ Bt,
                                               CT* __restrict__ C, int M, int N, int K) {
    __shared__ f16 As[128 * 32];
    __shared__ f16 Bs[128 * 32];
    const int tid  = threadIdx.x;
    const int wave = tid >> 6, lane = tid & 63;
    const int quad = lane >> 4, m16 = lane & 15;
    const int waveM = (wave >> 1) * 64, waveN = (wave & 1) * 64;
    const int bm = blockIdx.y * 128, bn = blockIdx.x * 128;

    f32x4 acc[4][4];
#pragma unroll
    for (int i = 0; i < 4; ++i)
#pragma unroll
        for (int j = 0; j < 4; ++j)
#pragma unroll
            for (int e = 0; e < 4; ++e) acc[i][j][e] = 0.f;

    const f16* gA[2]; const f16* gB[2]; f16* lA[2]; f16* lB[2];
#pragma unroll
    for (int it = 0; it < 2; ++it) {
        int slot = wave * 128 + it * 64 + lane;
        int row  = slot >> 2;
        int c    = (slot - (row >> 1)) & 3;          // inverse swizzle
        gA[it] = A  + (size_t)(bm + row) * K + c * 8;
        gB[it] = Bt + (size_t)(bn + row) * K + c * 8;
        lA[it] = As + (size_t)(wave * 128 + it * 64) * 8;
        lB[it] = Bs + (size_t)(wave * 128 + it * 64) * 8;
    }
    const f16* apf[4]; const f16* bpf[4];
#pragma unroll
    for (int t = 0; t < 4; ++t) {
        int rowA = waveM + t * 16 + m16;
        int rowB = waveN + t * 16 + m16;
        apf[t] = As + rowA * 32 + (((quad + (rowA >> 1)) & 3) * 8);
        bpf[t] = Bs + rowB * 32 + (((quad + (rowB >> 1)) & 3) * 8);
    }

    for (int k0 = 0; k0 < K; k0 += 32) {
        __syncthreads();
#pragma unroll
        for (int it = 0; it < 2; ++it) {
            GLOAD_LDS16(gA[it] + k0, lA[it]);
            GLOAD_LDS16(gB[it] + k0, lB[it]);
        }
        __syncthreads();
        f16x8 af[4], bf[4];
#pragma unroll
        for (int t = 0; t < 4; ++t) af[t] = *(const f16x8*)apf[t];
#pragma unroll
        for (int t = 0; t < 4; ++t) bf[t] = *(const f16x8*)bpf[t];
#pragma unroll
        for (int i = 0; i < 4; ++i)
#pragma unroll
            for (int j = 0; j < 4; ++j)
                acc[i][j] = __builtin_amdgcn_mfma_f32_16x16x32_f16(af[i], bf[j], acc[i][j], 0, 0, 0);
    }

#pragma unroll
    for (int i = 0; i < 4; ++i)
#pragma unroll
        for (int r = 0; r < 4; ++r) {
            int row = bm + waveM + i * 16 + quad * 4 + r;
#pragma unroll
            for (int j = 0; j < 4; ++j) {
                int col = bn + waveN + j * 16 + m16;
                C[(size_t)row * N + col] = (CT)acc[i][j][r];
            }
        }
}

// ---------------------------------------------------------------- RoPE (q,k only)
// Paged cache scatter+gather through an injective block_table is the identity on
// (b,s) -> skip the cache. qkv row: q 0:4096 | k 4096:5120 | v 5120:6144.
__global__ __launch_bounds__(256) void rope_qk(const f16* __restrict__ qkv,
                                               const float* __restrict__ freqs,
                                               f16* __restrict__ qh,
                                               f16* __restrict__ kk) {
    int idx  = blockIdx.x * 256 + threadIdx.x;     // B*S*40heads*64pairs
    int row  = idx / 2560;
    int p    = idx - row * 2560;
    int b    = row >> 11, s = row & 2047;
    int head = p >> 6, i = p & 63;
    const f16* src = qkv + (size_t)row * 6144 + head * 128 + 2 * i;
    float v0 = (float)src[0], v1 = (float)src[1];
    float c  = freqs[s * 128 + 2 * i];
    float sn = freqs[s * 128 + 2 * i + 1];
    float r0 = v0 * c - v1 * sn;
    float r1 = v1 * c + v0 * sn;
    f16* dst = (head < 32)
        ? qh + (((size_t)(b * 32 + head)) * 2048 + s) * 128 + 2 * i
        : kk + (((size_t)(b * 8 + head - 32)) * 2048 + s) * 128 + 2 * i;
    dst[0] = (f16)r0; dst[1] = (f16)r1;
}

// ---------------------------------------------------------------- V transpose (LDS-tiled)
__global__ __launch_bounds__(256) void transpose_v(const f16* __restrict__ qkv,
                                                   f16* __restrict__ vvt) {
    __shared__ f16 T[64][72];
    const int st = blockIdx.x, dt = blockIdx.y;
    const int b = blockIdx.z >> 3, kvh = blockIdx.z & 7;
    const int tid = threadIdx.x;
    const int sr = tid >> 3, c8 = (tid & 7) * 8;
#pragma unroll
    for (int rep = 0; rep < 2; ++rep) {
        int sl = rep * 32 + sr;
        *(f16x8*)&T[sl][c8] =
            *(const f16x8*)(qkv + (size_t)(b * 2048 + st * 64 + sl) * 6144
                            + 5120 + kvh * 128 + dt * 64 + c8);
    }
    __syncthreads();
#pragma unroll
    for (int rep = 0; rep < 2; ++rep) {
        int dl = rep * 32 + sr;
        f16x8 v;
#pragma unroll
        for (int j = 0; j < 8; ++j) v[j] = T[c8 + j][dl];
        *(f16x8*)(vvt + (((size_t)(b * 8 + kvh)) * 128 + dt * 64 + dl) * 2048
                  + st * 64 + c8) = v;
    }
}

// ---------------------------------------------------------------- flash attention v4
// Round-2 proven body (84 VGPR, no spill; Ps overlaid on Ks, 35.8 KB LDS -> 4 blk/CU)
// + uniform work pairing: block handles q-tiles {31-pair, pair} sequentially, so every
// block does exactly 33 k-tiles. Grid (16,32,2)=1024 blocks = exactly 4/CU, one
// co-resident scheduling wave, no causal tail.
__global__ __launch_bounds__(256) void attn_fused(const f16* __restrict__ qh,
                                                  const f16* __restrict__ kk,
                                                  const f16* __restrict__ vvt,
                                                  const int* __restrict__ seqlens,
                                                  f16* __restrict__ out) {
    __shared__ f16 KsPs[64 * 136];   // Ks: [key][d] stride 136; Ps overlays offset 0
    __shared__ f16 Vs[128][72];      // [d][key], stride 72 (2-way free)
    const int pair = blockIdx.x;     // 0..15
    const int h = blockIdx.y, b = blockIdx.z;
    const int kvh = h >> 2;
    const int tid = threadIdx.x, wave = tid >> 6, lane = tid & 63;
    const int quad = lane >> 4, m16 = lane & 15;
    f16* Ps = KsPs;

    const int seqlen = seqlens[b];
    const f16* kbp = kk  + ((size_t)(b * 8 + kvh) * 2048) * 128;
    const f16* vbp = vvt + ((size_t)(b * 8 + kvh) * 128) * 2048;

    for (int half = 0; half < 2; ++half) {
        const int qt = half ? pair : (31 - pair);   // heavy tile first
        const int qbase = qt * 64;
        const int qw = qbase + wave * 16;

        const f16* qptr = qh + (((size_t)(b * 32 + h)) * 2048 + qw + m16) * 128;
        f16x8 qf[4];
#pragma unroll
        for (int c = 0; c < 4; ++c) qf[c] = *(const f16x8*)(qptr + c * 32 + quad * 8);

        float m_i[4], l_i[4];
        f32x4 oacc[8];
#pragma unroll
        for (int r = 0; r < 4; ++r) { m_i[r] = NEG_INF; l_i[r] = 0.f; }
#pragma unroll
        for (int dt = 0; dt < 8; ++dt)
#pragma unroll
            for (int e = 0; e < 4; ++e) oacc[dt][e] = 0.f;

        int kmax = qbase + 64; if (seqlen < kmax) kmax = seqlen;

        for (int kt = 0; kt < kmax; kt += 64) {
            __syncthreads();   // prior Ks/Ps/Vs reads complete
#pragma unroll
            for (int it = 0; it < 4; ++it) {       // K tile: 64 keys x 128 d
                int g = it * 256 + tid;
                int r_ = g >> 4, c8 = (g & 15) * 8;
                *(f16x8*)&KsPs[r_ * 136 + c8] = *(const f16x8*)(kbp + (size_t)(kt + r_) * 128 + c8);
            }
#pragma unroll
            for (int it = 0; it < 4; ++it) {       // V^T tile: 128 d x 64 keys
                int g = it * 256 + tid;
                int r_ = g >> 3, c8 = (g & 7) * 8;
                *(f16x8*)&Vs[r_][c8] = *(const f16x8*)(vbp + (size_t)r_ * 2048 + kt + c8);
            }
            __syncthreads();

            // S = Q K^T
            f32x4 sc[4];
#pragma unroll
            for (int nt = 0; nt < 4; ++nt) {
                f32x4 s = {0.f, 0.f, 0.f, 0.f};
#pragma unroll
                for (int c = 0; c < 4; ++c) {
                    f16x8 kf = *(const f16x8*)&KsPs[(nt * 16 + m16) * 136 + c * 32 + quad * 8];
                    s = __builtin_amdgcn_mfma_f32_16x16x32_f16(qf[c], kf, s, 0, 0, 0);
                }
                sc[nt] = s;
            }

            // scale + mask + online softmax
            float sv[4][4];
            float mt[4] = {NEG_INF, NEG_INF, NEG_INF, NEG_INF};
#pragma unroll
            for (int nt = 0; nt < 4; ++nt) {
                int kpos = kt + nt * 16 + m16;
#pragma unroll
                for (int r = 0; r < 4; ++r) {
                    int qpos = qw + quad * 4 + r;
                    float sx = sc[nt][r] * 0.08838834764831845f;
                    sx = (kpos <= qpos && kpos < seqlen) ? sx : NEG_INF;
                    sv[nt][r] = sx;
                    mt[r] = fmaxf(mt[r], sx);
                }
            }
#pragma unroll
            for (int off = 1; off < 16; off <<= 1)
#pragma unroll
                for (int r = 0; r < 4; ++r)
                    mt[r] = fmaxf(mt[r], __shfl_xor(mt[r], off, 64));

            float alpha[4], mm[4];
#pragma unroll
            for (int r = 0; r < 4; ++r) {
                float mo = m_i[r];
                float mn = fmaxf(mo, mt[r]);
                float mmr = fmaxf(mn, -1e30f);
                alpha[r] = __expf(mo - mmr);
                m_i[r] = mn;
                mm[r] = mmr;
            }
            float rs[4] = {0.f, 0.f, 0.f, 0.f};
#pragma unroll
            for (int nt = 0; nt < 4; ++nt)
#pragma unroll
                for (int r = 0; r < 4; ++r) {
                    float pv = __expf(sv[nt][r] - mm[r]);
                    sv[nt][r] = pv;
                    rs[r] += pv;
                }
#pragma unroll
            for (int off = 1; off < 16; off <<= 1)
#pragma unroll
                for (int r = 0; r < 4; ++r) rs[r] += __shfl_xor(rs[r], off, 64);
#pragma unroll
            for (int r = 0; r < 4; ++r) l_i[r] = l_i[r] * alpha[r] + rs[r];
#pragma unroll
            for (int dt = 0; dt < 8; ++dt)
#pragma unroll
                for (int r = 0; r < 4; ++r) oacc[dt][r] *= alpha[r];

            __syncthreads();   // ALL waves done reading Ks before Ps overwrites

            // P: C-layout regs -> wave-private LDS region -> A-layout fragments
#pragma unroll
            for (int nt = 0; nt < 4; ++nt)
#pragma unroll
                for (int r = 0; r < 4; ++r)
                    Ps[(wave * 16 + quad * 4 + r) * 72 + nt * 16 + m16] = (f16)sv[nt][r];

            f16x8 pf[2];
#pragma unroll
            for (int c = 0; c < 2; ++c)
                pf[c] = *(const f16x8*)&Ps[(wave * 16 + m16) * 72 + c * 32 + quad * 8];
#pragma unroll
            for (int dt = 0; dt < 8; ++dt)
#pragma unroll
                for (int c = 0; c < 2; ++c) {
                    f16x8 vf = *(const f16x8*)&Vs[dt * 16 + m16][c * 32 + quad * 8];
                    oacc[dt] = __builtin_amdgcn_mfma_f32_16x16x32_f16(pf[c], vf, oacc[dt], 0, 0, 0);
                }
        }

        // normalize + write [B,S,NH*HD]
#pragma unroll
        for (int r = 0; r < 4; ++r) {
            int qpos = qw + quad * 4 + r;
            float inv = 1.0f / l_i[r];
            f16* op = out + ((size_t)b * 2048 + qpos) * 4096 + h * 128;
#pragma unroll
            for (int dt = 0; dt < 8; ++dt)
                op[dt * 16 + m16] = (f16)(oacc[dt][r] * inv);
        }
        // next half's k-loop starts with __syncthreads(), protecting LDS reuse
    }
}

// ---------------------------------------------------------------- launch
extern "C" void kernel_launch(void* const* d_in, const int* in_sizes, int n_in,
                              void* d_out, int out_size, void* d_ws, size_t ws_size,
                              hipStream_t stream) {
    const float* x     = (const float*)d_in[0];   // [2,2048,4096]
    const float* wqkv  = (const float*)d_in[1];   // [6144,4096]
    const float* wo    = (const float*)d_in[2];   // [4096,4096]
    const float* freqs = (const float*)d_in[3];   // [2048,1,64,2]
    const int*   seql  = (const int*)d_in[7];     // [2]
    float* out = (float*)d_out;

    char* ws = (char*)d_ws;
    size_t o = 0;
    f16* xh    = (f16*)(ws + o); o += (size_t)4096 * 4096 * 2;   // reused as attn_h
    f16* wqkvh = (f16*)(ws + o); o += (size_t)6144 * 4096 * 2;
    f16* woh   = (f16*)(ws + o); o += (size_t)4096 * 4096 * 2;
    f16* qkvh  = (f16*)(ws + o); o += (size_t)4096 * 6144 * 2;
    f16* qhp   = (f16*)(ws + o); o += (size_t)4096 * 4096 * 2;
    f16* kkp   = (f16*)(ws + o); o += (size_t)4096 * 8 * 128 * 2;
    f16* vvt   = (f16*)(ws + o); o += (size_t)4096 * 8 * 128 * 2;
    f16* attnh = xh;  // xh dead after GEMM1

    cvt_f32_f16<<<16384, 256, 0, stream>>>(x, xh, 4194304);
    cvt_f32_f16<<<24576, 256, 0, stream>>>(wqkv, wqkvh, 6291456);
    cvt_f32_f16<<<16384, 256, 0, stream>>>(wo, woh, 4194304);

    gemm_bt<f16><<<dim3(48, 32), 256, 0, stream>>>(xh, wqkvh, qkvh, 4096, 6144, 4096);

    rope_qk<<<40960, 256, 0, stream>>>(qkvh, freqs, qhp, kkp);
    transpose_v<<<dim3(32, 2, 16), 256, 0, stream>>>(qkvh, vvt);

    attn_fused<<<dim3(16, 32, 2), 256, 0, stream>>>(qhp, kkp, vvt, seql, attnh);

    gemm_bt<float><<<dim3(32, 32), 256, 0, stream>>>(attnh, woh, out, 4096, 4096, 4096);
}